// Round 1
// baseline (364823.486 us; speedup 1.0000x reference)
//
// SlimeMoldEncoder on MI355X — round 1.
// Decomposition:
//   Phase A (parallel): sense = tanh(src@Ws+b) -> bf16 ; xuz = src@Uz -> bf16   (big MFMA GEMMs)
//   Scan   (persistent, 208 WG x 512 thr, atomic grid barrier, 3 bar/step):
//       ph1: q = state@Wq, k = sense_t@Wk, v = sense_t@Wv, z = sigmoid(state@Wz + xuz_t)
//       ph2: vitality+softmax (chore WGs, flag-gated) ; flow = (alloc*v)@Wo (K-split x4)
//       ph3: state = z*state + (1-z)*tanh(flow); emit bf16 hi/lo split of state
//   Phase C (parallel): out = states@W_out + b  as split-bf16: hi@hi + hi@lo + lo@hi (fp32-quality)
// Workspace ≈ 1.07 GB. All weights pre-transposed+bf16 so MFMA B-fragments are contiguous ds_read_b128.

#include <hip/hip_runtime.h>
#include <cstdint>
#include <cstddef>

#define S_LEN 1024
#define BATCH 128
#define DM    1024
#define PHD   4096
#define SB    (S_LEN*BATCH)
#define NWG   208

typedef unsigned short u16;
typedef unsigned int   u32;
typedef __attribute__((ext_vector_type(8))) short short8;
typedef __attribute__((ext_vector_type(4))) float f32x4;

typedef const __attribute__((address_space(1))) void gas_void;
typedef __attribute__((address_space(3))) void las_void;

__device__ __forceinline__ u16 bf16r(float f){
  u32 x = __builtin_bit_cast(u32, f);
  x += 0x7fffu + ((x >> 16) & 1u);
  return (u16)(x >> 16);
}
__device__ __forceinline__ float bf2f(u16 u){
  return __builtin_bit_cast(float, (u32)u << 16);
}
__device__ __forceinline__ void gll16(const void* g, void* l){
  __builtin_amdgcn_global_load_lds((gas_void*)g, (las_void*)l, 16, 0, 0);
}

// ---------------- weight transpose + bf16 convert (optionally hi/lo split) ----------------
__global__ void __launch_bounds__(256) wtrans(const float* __restrict__ src, int R, int C,
                                              u16* __restrict__ dst, u16* __restrict__ dlo)
{
  __shared__ float tile[64][65];
  const int nct = C >> 6;
  const int rt = blockIdx.x / nct, ct = blockIdx.x % nct;
  const int r0 = rt << 6, c0 = ct << 6;
  for (int idx = threadIdx.x; idx < 4096; idx += 256){
    int r = idx >> 6, c = idx & 63;
    tile[r][c] = src[(size_t)(r0 + r)*C + (c0 + c)];
  }
  __syncthreads();
  for (int idx = threadIdx.x; idx < 4096; idx += 256){
    int n = idx >> 6, k = idx & 63;
    float wv = tile[k][n];
    u16 hi = bf16r(wv);
    size_t di = (size_t)(c0 + n)*R + (r0 + k);
    dst[di] = hi;
    if (dlo) dlo[di] = bf16r(wv - bf2f(hi));
  }
}

// ---------------- big batched GEMM: C[M,N] = A[M,K] @ BT[N,K]^T ----------------
// EPI: 0 raw->bf16, 1 tanh(x+bias)->bf16, 2 x+bias->f32, 3 f32 +=
template<int AF32, int EPI>
__global__ void __launch_bounds__(512) gemm_big(const void* __restrict__ Aptr,
    const u16* __restrict__ BT, const float* __restrict__ bias,
    float* __restrict__ Cf, u16* __restrict__ Cb, int M, int N, int K)
{
  __shared__ __align__(16) u16 As[128*32];
  __shared__ __align__(16) u16 Bs[128*32];
  const int ntc = N >> 7;
  const int mt = blockIdx.x / ntc, nt = blockIdx.x % ntc;
  const int tid = threadIdx.x;
  const int lane = tid & 63, wave = tid >> 6;
  const int wm = wave >> 1, wn = wave & 1;     // 4m x 2n wave grid over 128x128 tile
  const int arow = tid >> 2, ac8 = (tid & 3) << 3;

  f32x4 acc[2][4];
  #pragma unroll
  for (int i=0;i<2;i++)
    #pragma unroll
    for (int j=0;j<4;j++) acc[i][j] = (f32x4){0.f,0.f,0.f,0.f};

  const float* A32 = (const float*)Aptr + (size_t)(mt*128 + arow)*K + ac8;
  const u16*   A16 = (const u16*)Aptr   + (size_t)(mt*128 + arow)*K + ac8;
  const u16*   Bg  = BT + (size_t)(nt*128 + arow)*K + ac8;
  u16* adst = &As[tid << 3];
  u16* bdst = &Bs[tid << 3];

  for (int k0 = 0; k0 < K; k0 += 32){
    if constexpr (AF32){
      float4 f0 = *(const float4*)(A32 + k0);
      float4 f1 = *(const float4*)(A32 + k0 + 4);
      short8 v;
      v[0]=(short)bf16r(f0.x); v[1]=(short)bf16r(f0.y);
      v[2]=(short)bf16r(f0.z); v[3]=(short)bf16r(f0.w);
      v[4]=(short)bf16r(f1.x); v[5]=(short)bf16r(f1.y);
      v[6]=(short)bf16r(f1.z); v[7]=(short)bf16r(f1.w);
      *(short8*)adst = v;
    } else {
      gll16(A16 + k0, adst);
    }
    gll16(Bg + k0, bdst);
    __syncthreads();
    short8 af[2];
    #pragma unroll
    for (int mr=0;mr<2;mr++)
      af[mr] = *(const short8*)&As[(((wm<<5)+(mr<<4)+(lane&15))<<5) + ((lane>>4)<<3)];
    #pragma unroll
    for (int nr=0;nr<4;nr++){
      short8 bf = *(const short8*)&Bs[(((wn<<6)+(nr<<4)+(lane&15))<<5) + ((lane>>4)<<3)];
      #pragma unroll
      for (int mr=0;mr<2;mr++)
        acc[mr][nr] = __builtin_amdgcn_mfma_f32_16x16x32_bf16(af[mr], bf, acc[mr][nr], 0,0,0);
    }
    __syncthreads();
  }
  const int r4 = (lane>>4)<<2, cl = lane & 15;
  #pragma unroll
  for (int mr=0;mr<2;mr++)
    #pragma unroll
    for (int nr=0;nr<4;nr++)
      #pragma unroll
      for (int i=0;i<4;i++){
        const int row = mt*128 + (wm<<5) + (mr<<4) + r4 + i;
        const int col = nt*128 + (wn<<6) + (nr<<4) + cl;
        const size_t idx = (size_t)row*N + col;
        float v = acc[mr][nr][i];
        if constexpr (EPI==0)      Cb[idx] = bf16r(v);
        else if constexpr (EPI==1) Cb[idx] = bf16r(tanhf(v + bias[col]));
        else if constexpr (EPI==2) Cf[idx] = v + bias[col];
        else                       Cf[idx] += v;
      }
}

// ---------------- persistent scan kernel ----------------
struct ScanArgs {
  const u16 *WqT, *WkT, *WvT, *WzT, *WoT;
  const u16 *sense, *xuz;
  u16 *q_t, *k_t, *v_t;
  float *z_buf, *alloc, *flow, *state_f;
  u16 *state_bf, *st_hi, *st_lo;
  u32 *cnt;   // cnt[0] = grid barrier, cnt[1] = vitality-done flag
};

__global__ void __launch_bounds__(512) scan_kernel(ScanArgs a)
{
  const int g = blockIdx.x;
  const int tid = threadIdx.x;
  const int lane = tid & 63, wave = tid >> 6;
  const int half = tid >> 8, ii = tid & 255;

  __shared__ __align__(16) u16 As[128*64];   // 16 KB
  __shared__ __align__(16) u16 Bs[64*64];    // 8 KB
  __shared__ float smx[2][64];
  __shared__ float alds[64][16];

  u32 bgen = 0;
  auto bar = [&](){
    __threadfence();
    __syncthreads();
    bgen += NWG;
    if (tid == 0){
      __hip_atomic_fetch_add(a.cnt, 1u, __ATOMIC_ACQ_REL, __HIP_MEMORY_SCOPE_AGENT);
      while (__hip_atomic_load(a.cnt, __ATOMIC_ACQUIRE, __HIP_MEMORY_SCOPE_AGENT) < bgen)
        __builtin_amdgcn_s_sleep(2);
    }
    __syncthreads();
    __threadfence();
  };

  if (g < 128){
    for (int c = tid; c < DM; c += 512){
      a.state_f[g*DM + c] = 0.f;
      a.state_bf[g*DM + c] = 0;
    }
  }
  bar();

  for (int t = 0; t < S_LEN; ++t){
    //================ phase 1: q / k / v / z tile GEMMs [128 x 64], K=1024 ================
    {
      const u16 *Abase, *Bbase;
      int outsel, pod = 0, zj = 0;
      if (g < 64){        pod = g;     Abase = a.state_bf;                   Bbase = a.WqT + ((size_t)pod<<6)*DM; outsel = 0; }
      else if (g < 128){  pod = g-64;  Abase = a.sense + (size_t)t*BATCH*DM; Bbase = a.WkT + ((size_t)pod<<6)*DM; outsel = 1; }
      else if (g < 192){  pod = g-128; Abase = a.sense + (size_t)t*BATCH*DM; Bbase = a.WvT + ((size_t)pod<<6)*DM; outsel = 2; }
      else {              zj = g-192;  Abase = a.state_bf;                   Bbase = a.WzT + ((size_t)zj<<6)*DM;  outsel = 3; }

      f32x4 acc[4];
      #pragma unroll
      for (int i=0;i<4;i++) acc[i] = (f32x4){0.f,0.f,0.f,0.f};

      const u16* ga = Abase + (size_t)(tid>>2)*DM + ((tid&3)<<3);
      const u16* gb = Bbase + (size_t)(ii>>2)*DM + ((ii&3)<<3) + (half<<5);
      u16* bdst = &Bs[(half<<11) + (ii<<3)];

      for (int k0 = 0; k0 < DM; k0 += 64){
        gll16(ga + k0,      &As[tid<<3]);           // A sub-tile cols k0..k0+31
        gll16(ga + k0 + 32, &As[4096 + (tid<<3)]);  // A sub-tile cols k0+32..k0+63
        gll16(gb + k0,      bdst);                  // B [64][64] as two [64][32] subtiles
        __syncthreads();
        const int abr = ((wave<<4) + (lane&15)) << 5;
        const int koff = (lane>>4) << 3;
        #pragma unroll
        for (int kk=0;kk<2;kk++){
          short8 af = *(const short8*)&As[(kk<<12) + abr + koff];
          #pragma unroll
          for (int nr=0;nr<4;nr++){
            short8 bf = *(const short8*)&Bs[(kk<<11) + (((nr<<4)+(lane&15))<<5) + koff];
            acc[nr] = __builtin_amdgcn_mfma_f32_16x16x32_bf16(af, bf, acc[nr], 0,0,0);
          }
        }
        __syncthreads();
      }
      const int r4 = (lane>>4)<<2, cl = lane & 15;
      if (outsel <= 2){
        u16* dst = (outsel==0) ? a.q_t : (outsel==1) ? a.k_t : a.v_t;
        #pragma unroll
        for (int nr=0;nr<4;nr++)
          #pragma unroll
          for (int i=0;i<4;i++){
            int row = (wave<<4) + r4 + i;
            int col = (pod<<6) + (nr<<4) + cl;
            dst[(size_t)row*PHD + col] = bf16r(acc[nr][i]);
          }
      } else {
        #pragma unroll
        for (int nr=0;nr<4;nr++)
          #pragma unroll
          for (int i=0;i<4;i++){
            int row = (wave<<4) + r4 + i;
            int col = (zj<<6) + (nr<<4) + cl;
            float xv = bf2f(a.xuz[((size_t)t*BATCH + row)*DM + col]);
            float zz = 1.f/(1.f + expf(-(acc[nr][i] + xv)));
            a.z_buf[row*DM + col] = zz;
          }
      }
    }
    bar();
    //================ phase 2: vitality/softmax chore + flow GEMM (K-split x4) ================
    if (g < 128){
      const int s = g & 3, ntile = (g>>2) & 15, mt2 = g >> 6;
      if (tid == 0){
        const u32 tgt = (u32)(64*(t+1));
        while (__hip_atomic_load(a.cnt+1, __ATOMIC_ACQUIRE, __HIP_MEMORY_SCOPE_AGENT) < tgt)
          __builtin_amdgcn_s_sleep(2);
      }
      __syncthreads();
      __threadfence();
      for (int idx = tid; idx < 64*16; idx += 512){
        int r = idx >> 4, p = idx & 15;
        alds[r][p] = a.alloc[((mt2<<6) + r)*64 + (s<<4) + p];
      }
      __syncthreads();

      f32x4 acc2[2];
      acc2[0] = (f32x4){0.f,0.f,0.f,0.f};
      acc2[1] = (f32x4){0.f,0.f,0.f,0.f};
      const int wm = wave >> 1, wn = wave & 1;
      const int r = ii >> 2, c8 = ((ii&3)<<3) + (half<<5);
      const u16* vrow = a.v_t + (size_t)((mt2<<6) + r)*PHD + (s<<10) + c8;
      const u16* wrow = a.WoT + (size_t)((ntile<<6) + r)*PHD + (s<<10) + c8;
      u16* adst = &As[(half<<11) + (ii<<3)];
      u16* bdst = &Bs[(half<<11) + (ii<<3)];

      for (int k0 = 0; k0 < 1024; k0 += 64){
        short8 vv = *(const short8*)(vrow + k0);
        float al = alds[r][k0>>6];          // one pod per 64-wide K chunk
        short8 uv;
        #pragma unroll
        for (int e=0;e<8;e++) uv[e] = (short)bf16r(bf2f((u16)vv[e]) * al);
        *(short8*)adst = uv;
        gll16(wrow + k0, bdst);
        __syncthreads();
        const int koff = (lane>>4) << 3;
        #pragma unroll
        for (int kk=0;kk<2;kk++){
          short8 af = *(const short8*)&As[(kk<<11) + (((wm<<4)+(lane&15))<<5) + koff];
          #pragma unroll
          for (int nr=0;nr<2;nr++){
            short8 bf = *(const short8*)&Bs[(kk<<11) + (((wn<<5)+(nr<<4)+(lane&15))<<5) + koff];
            acc2[nr] = __builtin_amdgcn_mfma_f32_16x16x32_bf16(af, bf, acc2[nr], 0,0,0);
          }
        }
        __syncthreads();
      }
      const int r4 = (lane>>4)<<2, cl = lane & 15;
      #pragma unroll
      for (int nr=0;nr<2;nr++)
        #pragma unroll
        for (int i=0;i<4;i++){
          int row = (mt2<<6) + (wm<<4) + r4 + i;
          int col = (ntile<<6) + (wn<<5) + (nr<<4) + cl;
          a.flow[((size_t)s*BATCH + row)*DM + col] = acc2[nr][i];
        }
    } else if (g < 192){
      // vitality + softmax for 2 batch rows
      const int b0 = (g - 128) << 1;
      if (tid < 128){
        int bl = tid >> 6, p = tid & 63;
        const u16* qp = a.q_t + (size_t)(b0+bl)*PHD + (p<<6);
        const u16* kp = a.k_t + (size_t)(b0+bl)*PHD + (p<<6);
        float sum = 0.f;
        #pragma unroll 8
        for (int h=0;h<64;h++) sum += bf2f(qp[h]) * bf2f(kp[h]);
        smx[bl][p] = sum * 0.125f;   // 1/sqrt(64)
      }
      __syncthreads();
      if (tid < 2){
        float m = -1e30f;
        for (int p=0;p<64;p++) m = fmaxf(m, smx[tid][p]);
        float sden = 0.f;
        for (int p=0;p<64;p++) sden += expf(smx[tid][p] - m);
        float inv = 1.f / sden;
        for (int p=0;p<64;p++) a.alloc[(b0+tid)*64 + p] = expf(smx[tid][p] - m) * inv;
      }
      __threadfence();
      __syncthreads();
      if (tid == 0)
        __hip_atomic_fetch_add(a.cnt+1, 1u, __ATOMIC_ACQ_REL, __HIP_MEMORY_SCOPE_AGENT);
    }
    bar();
    //================ phase 3: gate update ================
    if (g < 128){
      const int b = g;
      const size_t so = (size_t)t*BATCH + b;
      for (int c = tid; c < DM; c += 512){
        float fl = a.flow[(size_t)b*DM + c]
                 + a.flow[((size_t)BATCH + b)*DM + c]
                 + a.flow[((size_t)2*BATCH + b)*DM + c]
                 + a.flow[((size_t)3*BATCH + b)*DM + c];
        float zz = a.z_buf[b*DM + c];
        float st = a.state_f[b*DM + c];
        float ns = zz*st + (1.f - zz)*tanhf(fl);
        a.state_f[b*DM + c] = ns;
        u16 hi = bf16r(ns);
        a.state_bf[b*DM + c] = hi;
        a.st_hi[so*DM + c] = hi;
        a.st_lo[so*DM + c] = bf16r(ns - bf2f(hi));
      }
    }
    bar();
  }
}

// ---------------- host launcher ----------------
extern "C" void kernel_launch(void* const* d_in, const int* in_sizes, int n_in,
                              void* d_out, int out_size, void* d_ws, size_t ws_size,
                              hipStream_t stream)
{
  (void)in_sizes; (void)n_in; (void)out_size;
  const float* src    = (const float*)d_in[0];
  const float* Wsense = (const float*)d_in[1];
  const float* bsense = (const float*)d_in[2];
  const float* Wq     = (const float*)d_in[3];
  const float* Wk     = (const float*)d_in[4];
  const float* Wv     = (const float*)d_in[5];
  const float* Wo     = (const float*)d_in[6];
  const float* Wz     = (const float*)d_in[7];
  const float* Uz     = (const float*)d_in[8];
  const float* Wout   = (const float*)d_in[9];
  const float* bout   = (const float*)d_in[10];
  float* out = (float*)d_out;

  char* base = (char*)d_ws;
  size_t o = 4096;
  auto take = [&](size_t bytes)->void*{
    void* r = base + o;
    o = (o + bytes + 255) & ~(size_t)255;
    return r;
  };
  u16* WsenseT = (u16*)take((size_t)DM*DM*2);
  u16* UzT     = (u16*)take((size_t)DM*DM*2);
  u16* WzT     = (u16*)take((size_t)DM*DM*2);
  u16* WoutTh  = (u16*)take((size_t)DM*DM*2);
  u16* WoutTl  = (u16*)take((size_t)DM*DM*2);
  u16* WqT     = (u16*)take((size_t)DM*PHD*2);
  u16* WkT     = (u16*)take((size_t)DM*PHD*2);
  u16* WvT     = (u16*)take((size_t)DM*PHD*2);
  u16* WoT     = (u16*)take((size_t)DM*PHD*2);
  u16* q_t     = (u16*)take((size_t)BATCH*PHD*2);
  u16* k_t     = (u16*)take((size_t)BATCH*PHD*2);
  u16* v_t     = (u16*)take((size_t)BATCH*PHD*2);
  float* z_buf = (float*)take((size_t)BATCH*DM*4);
  float* alloc_= (float*)take((size_t)BATCH*64*4);
  float* flow  = (float*)take((size_t)4*BATCH*DM*4);
  float* state_f = (float*)take((size_t)BATCH*DM*4);
  u16* state_bf  = (u16*)take((size_t)BATCH*DM*2);
  u16* sense   = (u16*)take((size_t)SB*DM*2);
  u16* xuz     = (u16*)take((size_t)SB*DM*2);
  u16* st_hi   = (u16*)take((size_t)SB*DM*2);
  u16* st_lo   = (u16*)take((size_t)SB*DM*2);
  if (o > ws_size) return;  // workspace insufficient — will surface as mismatch; redesign needed

  hipMemsetAsync(d_ws, 0, 4096, stream);  // zero barrier + flag counters

  wtrans<<<dim3(16*16), 256, 0, stream>>>(Wsense, DM, DM,  WsenseT, nullptr);
  wtrans<<<dim3(16*16), 256, 0, stream>>>(Uz,     DM, DM,  UzT,     nullptr);
  wtrans<<<dim3(16*16), 256, 0, stream>>>(Wz,     DM, DM,  WzT,     nullptr);
  wtrans<<<dim3(16*16), 256, 0, stream>>>(Wout,   DM, DM,  WoutTh,  WoutTl);
  wtrans<<<dim3(16*64), 256, 0, stream>>>(Wq,     DM, PHD, WqT,     nullptr);
  wtrans<<<dim3(16*64), 256, 0, stream>>>(Wk,     DM, PHD, WkT,     nullptr);
  wtrans<<<dim3(16*64), 256, 0, stream>>>(Wv,     DM, PHD, WvT,     nullptr);
  wtrans<<<dim3(64*16), 256, 0, stream>>>(Wo,     PHD, DM, WoT,     nullptr);

  gemm_big<1,1><<<dim3((SB/128)*(DM/128)), 512, 0, stream>>>(src, WsenseT, bsense, nullptr, sense, SB, DM, DM);
  gemm_big<1,0><<<dim3((SB/128)*(DM/128)), 512, 0, stream>>>(src, UzT, nullptr, nullptr, xuz, SB, DM, DM);

  ScanArgs sa;
  sa.WqT = WqT; sa.WkT = WkT; sa.WvT = WvT; sa.WzT = WzT; sa.WoT = WoT;
  sa.sense = sense; sa.xuz = xuz;
  sa.q_t = q_t; sa.k_t = k_t; sa.v_t = v_t;
  sa.z_buf = z_buf; sa.alloc = alloc_; sa.flow = flow; sa.state_f = state_f;
  sa.state_bf = state_bf; sa.st_hi = st_hi; sa.st_lo = st_lo;
  sa.cnt = (u32*)d_ws;
  scan_kernel<<<dim3(NWG), 512, 0, stream>>>(sa);

  // out = states @ W_out + b, split-bf16 for fp32-grade accuracy
  gemm_big<0,2><<<dim3((SB/128)*(DM/128)), 512, 0, stream>>>(st_hi, WoutTh, bout, out, nullptr, SB, DM, DM);
  gemm_big<0,3><<<dim3((SB/128)*(DM/128)), 512, 0, stream>>>(st_hi, WoutTl, nullptr, out, nullptr, SB, DM, DM);
  gemm_big<0,3><<<dim3((SB/128)*(DM/128)), 512, 0, stream>>>(st_lo, WoutTh, nullptr, out, nullptr, SB, DM, DM);
}